// Round 7
// baseline (3003.391 us; speedup 1.0000x reference)
//
#include <hip/hip_runtime.h>
#include <hip/hip_bf16.h>
#include <stdint.h>

// Persistent-RNN, R7: back to known-good medium (agent-scope/IC) to test the
// POLL-CONGESTION hypothesis + bisect the R5/R6 failure.
//  - R2/R3/R4 all pin at ~13k cyc/step across 3 very different protocols ->
//    fixed-RT story unconvincing; new theory: the spin-polls themselves congest
//    the IC fabric and inflate every round trip. R7 cuts standing poll traffic
//    ~50x: only wave 0 polls 16 flag dwords, s_sleep(2) backoff, barrier wakes
//    the other 7 waves.
//  - R4 spilled (VGPR_Count=128 vs ~250 live under launch_bounds(512,2)):
//    weight fragments reloaded from scratch every step. Now (512,1) -> 256 regs.
//  - Bisect probe: benign `s_getreg_b32 hwreg(HW_REG_XCC_ID)` (volatile, unused).
//    Same opaque failure again => the hwreg read killed R5/R6; pass => it's fine
//    and the sc0/XCD path died elsewhere.
//  - Layout: 128 blocks x 512 threads (8 waves). 8 batch-groups x 16 col-blocks;
//    block (g,m): rows [16g,16g+16), cols [64m,64m+64). W_hh/W_ih register-
//    resident bf16 hi+lo fragments. State: split hi/lo planes, double-buffered.
//  - Flag protocol (R3-proven, WAR-safe): end of step t sets flag=t+1 AFTER a
//    barrier that drains all waves' state stores (syncthreads emits per-wave
//    vmcnt(0)); consumer at step t polls all 16 flags >= t.

#define TSTEPS 512
#define BATCH  128
#define NI     256
#define NH     1024
#define NO     128
#define GROUPS 8
#define PRODS  16    // producers (col-blocks) per group
#define BG     16
#define COLS   64
#define NWAVE  8
#define FSTRIDE 16   // u32 stride between flags (64B: own line)

typedef __attribute__((ext_vector_type(8))) short s16x8;
typedef __attribute__((ext_vector_type(4))) short s16x4;
typedef __attribute__((ext_vector_type(4))) float f32x4;
typedef unsigned long long ull;

__device__ __forceinline__ unsigned short f2bf_rne(float f) {
  unsigned u = __builtin_bit_cast(unsigned, f);
  unsigned r = u + 0x7fffu + ((u >> 16) & 1u);
  return (unsigned short)(r >> 16);
}
__device__ __forceinline__ float bf2f(unsigned short h) {
  unsigned u = ((unsigned)h) << 16;
  return __builtin_bit_cast(float, u);
}
__device__ __forceinline__ void split_bf(float v, short &hi, short &lo) {
  unsigned short h = f2bf_rne(v);
  hi = (short)h;
  lo = (short)f2bf_rne(v - bf2f(h));
}
__device__ __forceinline__ f32x4 mfma16(s16x8 a, s16x8 b, f32x4 c) {
  return __builtin_amdgcn_mfma_f32_16x16x32_bf16(a, b, c, 0, 0, 0);
}
__device__ __forceinline__ float fast_tanh(float a) {
  float cl = fminf(fmaxf(a, -15.f), 15.f);
  float e  = __expf(2.f * cl);
  return (e - 1.f) / (e + 1.f);
}
__device__ __forceinline__ s16x8 cat8(ull a, ull b) {
  s16x4 xx = __builtin_bit_cast(s16x4, a);
  s16x4 yy = __builtin_bit_cast(s16x4, b);
  return __builtin_shufflevector(xx, yy, 0, 1, 2, 3, 4, 5, 6, 7);
}

__global__ __launch_bounds__(512, 1)
void rnn_persistent(const float* __restrict__ x,
                    const float* __restrict__ W_ih,
                    const float* __restrict__ W_hh,
                    const float* __restrict__ b_ih,
                    const float* __restrict__ b_hh,
                    unsigned short* __restrict__ SH,   // [2][128][1024] bf16 hi plane
                    unsigned short* __restrict__ SL,   // [2][128][1024] bf16 lo plane
                    unsigned*       __restrict__ flags)// [8][16][FSTRIDE]
{
  const int tid  = threadIdx.x;
  const int wave = tid >> 6;
  const int lane = tid & 63;
  const int lr   = lane & 15;
  const int lq   = lane >> 4;
  const int g    = blockIdx.x >> 4;    // 8 groups
  const int m    = blockIdx.x & 15;    // 16 col-blocks per group

  // ---- bisect probe: does hwreg(HW_REG_XCC_ID) assemble/run on this stack? ----
  unsigned xcc_probe;
  asm volatile("s_getreg_b32 %0, hwreg(HW_REG_XCC_ID)" : "=s"(xcc_probe));
  (void)xcc_probe;

  const int row0 = g * BG;
  const int h0   = m * COLS;
  const int kq0  = wave * 128;         // this wave's hidden-K slice
  const int iq0  = wave * 32;          // this wave's input-K slice

  __shared__ float red[2][NWAVE][1024];

  // ---- persistent W_hh B-fragments: [n-tile 0..3][kb 0..3], hi/lo ----
  // B[k][n] = W_hh[h0+n][k]; lane holds n = lane&15, k = kq0+kb*32+lq*8+j.
  s16x8 whh_hi[4][4], whh_lo[4][4];
  #pragma unroll
  for (int nt = 0; nt < 4; ++nt) {
    const int h = h0 + nt * 16 + lr;
    #pragma unroll
    for (int kb = 0; kb < 4; ++kb) {
      const float* p = W_hh + (size_t)h * NH + kq0 + kb * 32 + lq * 8;
      s16x8 hi, lo;
      #pragma unroll
      for (int j = 0; j < 8; ++j) { short a, b; split_bf(p[j], a, b); hi[j] = a; lo[j] = b; }
      whh_hi[nt][kb] = hi; whh_lo[nt][kb] = lo;
    }
  }
  // ---- persistent W_ih B-fragments: [n-tile 0..3], one 32-wide kb ----
  s16x8 wih_hi[4], wih_lo[4];
  #pragma unroll
  for (int nt = 0; nt < 4; ++nt) {
    const int h = h0 + nt * 16 + lr;
    const float* p = W_ih + (size_t)h * NI + iq0 + lq * 8;
    s16x8 hi, lo;
    #pragma unroll
    for (int j = 0; j < 8; ++j) { short a, b; split_bf(p[j], a, b); hi[j] = a; lo[j] = b; }
    wih_hi[nt] = hi; wih_lo[nt] = lo;
  }

  // epilogue ownership: thread -> row tid>>5 (0..15), cols 2*(tid&31), +1
  const int er = tid >> 5;
  const int ec = (tid & 31) * 2;
  const float bias0 = b_ih[h0 + ec]     + b_hh[h0 + ec];
  const float bias1 = b_ih[h0 + ec + 1] + b_hh[h0 + ec + 1];

  unsigned*       myflag   = flags + (g * PRODS + m) * FSTRIDE;
  const unsigned* pollflag = flags + (g * PRODS + (lane & 15)) * FSTRIDE;

  for (int t = 0; t < TSTEPS; ++t) {
    // ---------- x loads + projection (overlaps producers' flag flight) ----------
    f32x4 acc[4];
    #pragma unroll
    for (int nt = 0; nt < 4; ++nt) acc[nt] = (f32x4){0.f, 0.f, 0.f, 0.f};
    {
      const float* xp = x + (size_t)t * BATCH * NI + (size_t)(row0 + lr) * NI + iq0 + lq * 8;
      s16x8 xhi, xlo;
      #pragma unroll
      for (int j = 0; j < 8; ++j) { short a, b; split_bf(xp[j], a, b); xhi[j] = a; xlo[j] = b; }
      #pragma unroll
      for (int nt = 0; nt < 4; ++nt) {
        acc[nt] = mfma16(xhi, wih_hi[nt], acc[nt]);
        acc[nt] = mfma16(xhi, wih_lo[nt], acc[nt]);
        acc[nt] = mfma16(xlo, wih_hi[nt], acc[nt]);
      }
    }
    // ---------- wave0-only lane-parallel flag poll with s_sleep backoff ----------
    if (t > 0 && wave == 0) {
      for (;;) {
        unsigned v = __hip_atomic_load(pollflag, __ATOMIC_RELAXED, __HIP_MEMORY_SCOPE_AGENT);
        if (__all((int)(v >= (unsigned)t))) break;
        __builtin_amdgcn_s_sleep(2);   // ~128 cyc backoff: cuts standing IC poll traffic
      }
    }
    __syncthreads();                    // barrier A: release all waves past the poll
    // ---------- state fragment loads (agent-scope/IC, split planes) ----------
    const ull* hb = (const ull*)(SH + (size_t)(t & 1) * (BATCH * NH)
                                 + (size_t)(row0 + lr) * NH + kq0 + lq * 8);
    const ull* lb = (const ull*)(SL + (size_t)(t & 1) * (BATCH * NH)
                                 + (size_t)(row0 + lr) * NH + kq0 + lq * 8);
    s16x8 shf[4], slf[4];
    #pragma unroll
    for (int kb = 0; kb < 4; ++kb) {
      ull ha  = __hip_atomic_load(hb + kb * 8,     __ATOMIC_RELAXED, __HIP_MEMORY_SCOPE_AGENT);
      ull hbv = __hip_atomic_load(hb + kb * 8 + 1, __ATOMIC_RELAXED, __HIP_MEMORY_SCOPE_AGENT);
      ull la  = __hip_atomic_load(lb + kb * 8,     __ATOMIC_RELAXED, __HIP_MEMORY_SCOPE_AGENT);
      ull lbv = __hip_atomic_load(lb + kb * 8 + 1, __ATOMIC_RELAXED, __HIP_MEMORY_SCOPE_AGENT);
      shf[kb] = cat8(ha, hbv);
      slf[kb] = cat8(la, lbv);
    }
    // ---------- recurrent MFMAs (fragments ready, zero unpack) ----------
    #pragma unroll
    for (int kb = 0; kb < 4; ++kb) {
      #pragma unroll
      for (int nt = 0; nt < 4; ++nt) {
        acc[nt] = mfma16(shf[kb], whh_hi[nt][kb], acc[nt]);
        acc[nt] = mfma16(shf[kb], whh_lo[nt][kb], acc[nt]);
        acc[nt] = mfma16(slf[kb], whh_hi[nt][kb], acc[nt]);
      }
    }
    // ---------- cross-wave K reduction (double-buffered red) ----------
    // C/D layout: col = lane&15, row = quad*4 + reg (m89/m91 verified)
    const int rbi = t & 1;
    #pragma unroll
    for (int nt = 0; nt < 4; ++nt)
      #pragma unroll
      for (int r = 0; r < 4; ++r)
        red[rbi][wave][(lq * 4 + r) * 64 + nt * 16 + lr] = acc[nt][r];
    __syncthreads();                    // barrier B: red[] write -> read
    // ---------- epilogue: reduce 8 waves, tanh, split, store ----------
    {
      float s0 = bias0, s1 = bias1;
      #pragma unroll
      for (int w = 0; w < NWAVE; ++w) {
        float2 v = *(const float2*)&red[rbi][w][er * 64 + ec];
        s0 += v.x; s1 += v.y;
      }
      float t0 = fast_tanh(s0), t1 = fast_tanh(s1);
      unsigned short h0b = f2bf_rne(t0);
      unsigned short l0b = f2bf_rne(t0 - bf2f(h0b));
      unsigned short h1b = f2bf_rne(t1);
      unsigned short l1b = f2bf_rne(t1 - bf2f(h1b));
      const size_t off = (size_t)((t + 1) & 1) * (BATCH * NH)
                       + (size_t)(row0 + er) * NH + h0 + ec;
      __hip_atomic_store((unsigned*)(SH + off), (unsigned)h0b | ((unsigned)h1b << 16),
                         __ATOMIC_RELAXED, __HIP_MEMORY_SCOPE_AGENT);
      __hip_atomic_store((unsigned*)(SL + off), (unsigned)l0b | ((unsigned)l1b << 16),
                         __ATOMIC_RELAXED, __HIP_MEMORY_SCOPE_AGENT);
    }
    __syncthreads();   // barrier C: every wave drains own vmcnt(0) -> all stores IC-visible
    if (tid == 0)
      __hip_atomic_store(myflag, (unsigned)(t + 1), __ATOMIC_RELAXED, __HIP_MEMORY_SCOPE_AGENT);
  }
}

__global__ __launch_bounds__(512)
void rnn_readout(const unsigned short* __restrict__ SH,  // final state hi plane (buf0)
                 const unsigned short* __restrict__ SL,  // final state lo plane (buf0)
                 const float* __restrict__ W_ro,          // [128][1024]
                 const float* __restrict__ b_ro,          // [128]
                 float* __restrict__ out)                 // [128][128]
{
  __shared__ float srow[4][NH];
  const int b0 = blockIdx.x * 4;
  for (int i = threadIdx.x; i < 4 * NH; i += 512) {
    const size_t idx = (size_t)(b0 + (i >> 10)) * NH + (i & 1023);
    srow[i >> 10][i & 1023] = bf2f(SH[idx]) + bf2f(SL[idx]);
  }
  __syncthreads();
  const int bb = threadIdx.x >> 7;
  const int o  = threadIdx.x & 127;
  const float* wr = W_ro + (size_t)o * NH;
  float s = 0.f;
  #pragma unroll 4
  for (int k = 0; k < NH; ++k) s += srow[bb][k] * wr[k];
  out[(size_t)(b0 + bb) * NO + o] = s + b_ro[o];
}

extern "C" void kernel_launch(void* const* d_in, const int* in_sizes, int n_in,
                              void* d_out, int out_size, void* d_ws, size_t ws_size,
                              hipStream_t stream) {
  (void)in_sizes; (void)n_in; (void)out_size; (void)ws_size;
  const float* x    = (const float*)d_in[0];
  const float* W_ih = (const float*)d_in[1];
  const float* W_hh = (const float*)d_in[2];
  const float* b_ih = (const float*)d_in[3];
  const float* b_hh = (const float*)d_in[4];
  const float* W_ro = (const float*)d_in[5];
  const float* b_ro = (const float*)d_in[6];
  float* out = (float*)d_out;

  unsigned short* SH = (unsigned short*)d_ws;          // [2][128][1024] bf16 hi (512 KB)
  unsigned short* SL = SH + 2 * BATCH * NH;            // [2][128][1024] bf16 lo (512 KB)
  unsigned* flags = (unsigned*)(SL + 2 * BATCH * NH);  // 8*16*FSTRIDE u32 (8 KB)

  // state_0 = 0 (buf0 of both planes), flags = 0
  hipMemsetAsync(SH, 0, (size_t)BATCH * NH * sizeof(unsigned short), stream);
  hipMemsetAsync(SL, 0, (size_t)BATCH * NH * sizeof(unsigned short), stream);
  hipMemsetAsync(flags, 0, (size_t)GROUPS * PRODS * FSTRIDE * sizeof(unsigned), stream);

  rnn_persistent<<<GROUPS * PRODS, 512, 0, stream>>>(x, W_ih, W_hh, b_ih, b_hh, SH, SL, flags);
  // T=512 even -> final state in buf0
  rnn_readout<<<BATCH / 4, 512, 0, stream>>>(SH, SL, W_ro, b_ro, out);
}